// Round 7
// baseline (598.655 us; speedup 1.0000x reference)
//
#include <hip/hip_runtime.h>

#define NBQ 12544
#define DM  256
#define MM  2048

typedef __attribute__((ext_vector_type(8)))  __bf16 bf16x8;
typedef __attribute__((ext_vector_type(4)))  float  floatx4;
typedef __attribute__((ext_vector_type(16))) float  floatx16;

__device__ __forceinline__ ushort f2bf(float x) {
    unsigned u = __float_as_uint(x);
    u += 0x7fffu + ((u >> 16) & 1u);   // RNE
    return (ushort)(u >> 16);
}
__device__ __forceinline__ float bf2f(ushort h) {
    return __uint_as_float(((unsigned)h) << 16);
}

// ---------------- ALL projections in one launch: C = A(fp32) * W(fp32)^T, bf16 out ----
__global__ __launch_bounds__(256) void gemm_proj_all(
    const float* __restrict__ x,      const float* __restrict__ ch_mem,
    const float* __restrict__ ch_wq,  const float* __restrict__ ch_wk,
    const float* __restrict__ ch_wv,  const float* __restrict__ sp_mem,
    const float* __restrict__ sp_wq,  const float* __restrict__ sp_wk,
    const float* __restrict__ sp_wv,
    ushort* __restrict__ Qb,  ushort* __restrict__ QFb,
    ushort* __restrict__ Kb,  ushort* __restrict__ KFb,
    ushort* __restrict__ Vtb, ushort* __restrict__ VFtb)
{
    __shared__ ushort As[64][72];
    __shared__ ushort Ws[64][72];

    int bid = blockIdx.x;
    const float* A; const float* W; ushort* C; int nrows, trans;
    if (bid < 1568) {
        if (bid < 784) { A = x; W = ch_wq; C = Qb; }
        else           { A = x; W = sp_wq; C = QFb; bid -= 784; }
        nrows = NBQ; trans = 0;
    } else if (bid < 1824) {
        if (bid < 1696) { A = ch_mem; W = ch_wk; C = Kb;  bid -= 1568; }
        else            { A = sp_mem; W = sp_wk; C = KFb; bid -= 1696; }
        nrows = MM; trans = 0;
    } else {
        if (bid < 1952) { A = ch_mem; W = ch_wv; C = Vtb;  bid -= 1824; }
        else            { A = sp_mem; W = sp_wv; C = VFtb; bid -= 1952; }
        nrows = MM; trans = 1;
    }
    const int r0 = (bid >> 2) * 64;
    const int c0 = (bid & 3) * 64;

    const int tid  = threadIdx.x;
    const int wv   = tid >> 6;
    const int lane = tid & 63;
    const int quad = lane >> 4;
    const int l16  = lane & 15;
    const int rw = (wv & 1) * 32;
    const int cw = (wv >> 1) * 32;

    floatx4 acc[2][2];
    #pragma unroll
    for (int i = 0; i < 2; ++i)
        #pragma unroll
        for (int j = 0; j < 2; ++j)
            acc[i][j] = (floatx4){0.f, 0.f, 0.f, 0.f};

    for (int d0 = 0; d0 < 256; d0 += 64) {
        __syncthreads();
        #pragma unroll
        for (int it = 0; it < 4; ++it) {
            int idx = tid + it * 256;
            int r = idx >> 4, c4 = (idx & 15) * 4;
            float4 a4 = *(const float4*)(A + (size_t)(r0 + r) * 256 + d0 + c4);
            float4 w4 = *(const float4*)(W + (size_t)(c0 + r) * 256 + d0 + c4);
            ushort4 ab, wb;
            ab.x = f2bf(a4.x); ab.y = f2bf(a4.y); ab.z = f2bf(a4.z); ab.w = f2bf(a4.w);
            wb.x = f2bf(w4.x); wb.y = f2bf(w4.y); wb.z = f2bf(w4.z); wb.w = f2bf(w4.w);
            *(ushort4*)&As[r][c4] = ab;
            *(ushort4*)&Ws[r][c4] = wb;
        }
        __syncthreads();
        #pragma unroll
        for (int kk = 0; kk < 64; kk += 32) {
            bf16x8 aA0 = *(const bf16x8*)&As[rw + l16][kk + quad * 8];
            bf16x8 aA1 = *(const bf16x8*)&As[rw + 16 + l16][kk + quad * 8];
            bf16x8 bW0 = *(const bf16x8*)&Ws[cw + l16][kk + quad * 8];
            bf16x8 bW1 = *(const bf16x8*)&Ws[cw + 16 + l16][kk + quad * 8];
            acc[0][0] = __builtin_amdgcn_mfma_f32_16x16x32_bf16(aA0, bW0, acc[0][0], 0, 0, 0);
            acc[0][1] = __builtin_amdgcn_mfma_f32_16x16x32_bf16(aA0, bW1, acc[0][1], 0, 0, 0);
            acc[1][0] = __builtin_amdgcn_mfma_f32_16x16x32_bf16(aA1, bW0, acc[1][0], 0, 0, 0);
            acc[1][1] = __builtin_amdgcn_mfma_f32_16x16x32_bf16(aA1, bW1, acc[1][1], 0, 0, 0);
        }
    }

    if (!trans) {
        #pragma unroll
        for (int ag = 0; ag < 2; ++ag)
            #pragma unroll
            for (int cg = 0; cg < 2; ++cg)
                #pragma unroll
                for (int i = 0; i < 4; ++i)
                    C[(size_t)(r0 + rw + ag * 16 + quad * 4 + i) * 256
                      + c0 + cw + cg * 16 + l16] = f2bf(acc[ag][cg][i]);
    } else {
        __syncthreads();
        #pragma unroll
        for (int ag = 0; ag < 2; ++ag)
            #pragma unroll
            for (int cg = 0; cg < 2; ++cg)
                #pragma unroll
                for (int i = 0; i < 4; ++i)
                    Ws[cw + cg * 16 + l16][rw + ag * 16 + quad * 4 + i] = f2bf(acc[ag][cg][i]);
        __syncthreads();
        const int col = tid >> 2;
        const int seg = (tid & 3) * 16;
        #pragma unroll
        for (int j = 0; j < 2; ++j)
            *(uint4*)(C + (size_t)(c0 + col) * nrows + r0 + seg + j * 8) =
                *(const uint4*)&Ws[col][seg + j * 8];
    }
}

// ---------------- row stats (QF rows then KF rows), one launch ----------------
__global__ __launch_bounds__(256) void row_stats_all(
    const ushort* __restrict__ QFb, const ushort* __restrict__ KFb,
    float* __restrict__ qm, float* __restrict__ qv,
    float* __restrict__ km, float* __restrict__ kv)
{
    const int rt   = blockIdx.x * 4 + (threadIdx.x >> 6);
    const int lane = threadIdx.x & 63;
    const ushort* X; float* mean; float* var; int row;
    if (rt < NBQ) { X = QFb; mean = qm; var = qv; row = rt; }
    else          { X = KFb; mean = km; var = kv; row = rt - NBQ; }
    ushort4 u = *(const ushort4*)(X + (size_t)row * 256 + lane * 4);
    float a = bf2f(u.x), b = bf2f(u.y), c = bf2f(u.z), d = bf2f(u.w);
    float s  = a + b + c + d;
    float ss = a * a + b * b + c * c + d * d;
    #pragma unroll
    for (int off = 32; off > 0; off >>= 1) {
        s  += __shfl_down(s, off);
        ss += __shfl_down(ss, off);
    }
    if (lane == 0) {
        float m = s * (1.f / 256.f);
        mean[row] = m;
        var[row]  = (ss - 256.f * m * m) * (1.f / 255.f);
    }
}

// ---------------- fused attention, key-split, LDS-aliased K/Vt ----------------
// grid 784: bid&1 = key-split (1024 keys each); (bid>>1) selects branch x 64q-block.
// LDS: kv_buf holds K[64][264] during score, Vt[256][72] during PV (staged after the
// score barrier). 46592 B total -> 3 blocks/CU. Partial softmax (no max-sub) is
// additive: blocks atomicAdd raw numerators + per-branch denominators; norm_combine
// finishes.
__global__ __launch_bounds__(256, 3) void fused_attn_split(
    const ushort* __restrict__ Qb,  const ushort* __restrict__ QFb,
    const ushort* __restrict__ Kb,  const ushort* __restrict__ KFb,
    const ushort* __restrict__ Vtb, const ushort* __restrict__ VFtb,
    const float* __restrict__ qm_, const float* __restrict__ qv_,
    const float* __restrict__ km_, const float* __restrict__ kv_,
    float* __restrict__ ch_num, float* __restrict__ sp_num,
    float* __restrict__ den_ch, float* __restrict__ den_sp)
{
    __shared__ ushort kv_buf[18432];    // K view: [64][264] (16896 us) / Vt view: [256][72]
    __shared__ ushort P_lds[64][72];    // [q][key], 144B stride (conflict-free, r6-proven)
    __shared__ float  denbuf[2][64];
    ushort (*K_lds)[264] = (ushort(*)[264])kv_buf;
    ushort (*Vt_lds)[72] = (ushort(*)[72])kv_buf;
    // total LDS = 36864 + 9216 + 512 = 46592 B -> 3 blocks/CU

    const int tid  = threadIdx.x;
    const int wv   = tid >> 6;
    const int lane = tid & 63;
    const int l32  = lane & 31;
    const int half = lane >> 5;

    int bid = blockIdx.x;
    const int ksp = bid & 1; bid >>= 1;
    const bool spatial = (bid >= 196);
    const int q0 = (spatial ? bid - 196 : bid) * 64;
    const ushort* Qp = spatial ? QFb  : Qb;
    const ushort* Kp = spatial ? KFb  : Kb;
    const ushort* Vp = spatial ? VFtb : Vtb;
    float* numout = spatial ? sp_num : ch_num;
    float* deng   = spatial ? den_sp : den_ch;

    const int qs = wv & 1;    // score-role: q half
    const int ks = wv >> 1;   // score-role: key half of the 64-tile

    // Q A-fragments in registers for the whole key loop: A[m=l32][k]
    bf16x8 aQ[16];
    {
        const ushort* qp = Qp + (size_t)(q0 + qs * 32 + l32) * DM + half * 8;
        #pragma unroll
        for (int s = 0; s < 16; ++s) aQ[s] = *(const bf16x8*)(qp + s * 16);
    }
    float qmr[16], qvr[16];
    if (spatial) {
        #pragma unroll
        for (int reg = 0; reg < 16; ++reg) {
            int row = q0 + qs * 32 + (reg & 3) + 8 * (reg >> 2) + 4 * half;
            qmr[reg] = qm_[row]; qvr[reg] = qv_[row];
        }
    }

    floatx16 accO[2][2];   // [q-tile][d-subtile], d-quarter = wv*64
    #pragma unroll
    for (int a = 0; a < 2; ++a)
        #pragma unroll
        for (int b = 0; b < 2; ++b)
            #pragma unroll
            for (int i = 0; i < 16; ++i) accO[a][b][i] = 0.f;
    float den_r[16];
    #pragma unroll
    for (int i = 0; i < 16; ++i) den_r[i] = 0.f;

    const int kt0 = ksp * 1024;
    for (int kt = kt0; kt < kt0 + 1024; kt += 64) {
        __syncthreads();  // prev iter's Vt/P reads done -> safe to restage K
        #pragma unroll
        for (int it = 0; it < 8; ++it) {
            int idx = tid + it * 256;
            int r = idx >> 5, c8 = (idx & 31) * 8;
            *(uint4*)&K_lds[r][c8] = *(const uint4*)(Kp + (size_t)(kt + r) * DM + c8);
        }
        __syncthreads();

        // ---- scores: 32q x 32k per wave, K=256 ----
        floatx16 S;
        #pragma unroll
        for (int i = 0; i < 16; ++i) S[i] = 0.f;
        #pragma unroll
        for (int s = 0; s < 16; ++s) {
            bf16x8 bK = *(const bf16x8*)&K_lds[ks * 32 + l32][s * 16 + half * 8];
            S = __builtin_amdgcn_mfma_f32_32x32x16_bf16(aQ[s], bK, S, 0, 0, 0);
        }
        // ---- epilogue -> P (bf16) + den partials ----
        {
            int kcol = kt + ks * 32 + l32;
            float kmv = 0.f, kvv = 0.f;
            if (spatial) { kmv = km_[kcol]; kvv = kv_[kcol]; }
            #pragma unroll
            for (int reg = 0; reg < 16; ++reg) {
                float p;
                if (!spatial) {
                    p = __expf(S[reg] * 0.0625f);
                } else {
                    float mp  = qmr[reg] * kmv;
                    float cov = (S[reg] - 256.f * mp) * (1.f / 255.f);
                    float num = (2.f * mp + 0.01f) * (2.f * cov + 0.03f);
                    float den = (qmr[reg] * qmr[reg] + kmv * kmv + 0.01f) * (qvr[reg] + kvv + 0.03f);
                    p = __expf(num / (den + 1e-8f));
                }
                int rloc = qs * 32 + (reg & 3) + 8 * (reg >> 2) + 4 * half;
                P_lds[rloc][ks * 32 + l32] = f2bf(p);
                den_r[reg] += p;
            }
        }
        __syncthreads();  // K reads + P writes done -> safe to overwrite kv_buf with Vt

        // stage Vt (256 d x 64 keys): 2048 uint4 = 256 rows x 8 chunks
        #pragma unroll
        for (int it = 0; it < 8; ++it) {
            int idx = tid + it * 256;
            int d = idx >> 3, k8 = (idx & 7) * 8;
            *(uint4*)&Vt_lds[d][k8] = *(const uint4*)(Vp + (size_t)d * MM + kt + k8);
        }
        __syncthreads();

        // ---- PV: wave = d-quarter (wv*64), A=P rows, B=Vt rows, 4 k-chunks ----
        #pragma unroll
        for (int kc = 0; kc < 4; ++kc) {
            bf16x8 aP0 = *(const bf16x8*)&P_lds[l32][kc * 16 + half * 8];
            bf16x8 aP1 = *(const bf16x8*)&P_lds[32 + l32][kc * 16 + half * 8];
            bf16x8 bV0 = *(const bf16x8*)&Vt_lds[wv * 64 + l32][kc * 16 + half * 8];
            bf16x8 bV1 = *(const bf16x8*)&Vt_lds[wv * 64 + 32 + l32][kc * 16 + half * 8];
            accO[0][0] = __builtin_amdgcn_mfma_f32_32x32x16_bf16(aP0, bV0, accO[0][0], 0, 0, 0);
            accO[0][1] = __builtin_amdgcn_mfma_f32_32x32x16_bf16(aP0, bV1, accO[0][1], 0, 0, 0);
            accO[1][0] = __builtin_amdgcn_mfma_f32_32x32x16_bf16(aP1, bV0, accO[1][0], 0, 0, 0);
            accO[1][1] = __builtin_amdgcn_mfma_f32_32x32x16_bf16(aP1, bV1, accO[1][1], 0, 0, 0);
        }
    }

    // ---- partial denominators: reduce over 32 key-cols, combine ks-halves ----
    #pragma unroll
    for (int reg = 0; reg < 16; ++reg)
        #pragma unroll
        for (int m = 1; m < 32; m <<= 1)
            den_r[reg] += __shfl_xor(den_r[reg], m, 64);
    if (l32 == 0) {
        #pragma unroll
        for (int reg = 0; reg < 16; ++reg) {
            int rloc = qs * 32 + (reg & 3) + 8 * (reg >> 2) + 4 * half;
            denbuf[ks][rloc] = den_r[reg];
        }
    }
    __syncthreads();
    if (tid < 64)
        atomicAdd(deng + q0 + tid, denbuf[0][tid] + denbuf[1][tid]);

    // ---- raw numerator partials: atomicAdd (additive across splits/blocks) ----
    #pragma unroll
    for (int qt = 0; qt < 2; ++qt) {
        #pragma unroll
        for (int reg = 0; reg < 16; ++reg) {
            int rloc = qt * 32 + (reg & 3) + 8 * (reg >> 2) + 4 * half;
            float* orow = numout + (size_t)(q0 + rloc) * DM + wv * 64 + l32;
            atomicAdd(orow,      accO[qt][0][reg]);
            atomicAdd(orow + 32, accO[qt][1][reg]);
        }
    }
}

// ---------------- final: out = ch_num/den_ch + sp_num/den_sp ----------------
__global__ __launch_bounds__(256) void norm_combine(
    float* __restrict__ out, const float* __restrict__ sp_num,
    const float* __restrict__ den_ch, const float* __restrict__ den_sp)
{
    int t = blockIdx.x * 256 + threadIdx.x;   // float4 index; NBQ*256/4 total
    int row = t >> 6;
    float rdc = 1.f / den_ch[row];
    float rds = 1.f / den_sp[row];
    float4 oc = ((const float4*)out)[t];
    float4 os = ((const float4*)sp_num)[t];
    float4 o;
    o.x = oc.x * rdc + os.x * rds;
    o.y = oc.y * rdc + os.y * rds;
    o.z = oc.z * rdc + os.z * rds;
    o.w = oc.w * rdc + os.w * rds;
    ((float4*)out)[t] = o;
}

extern "C" void kernel_launch(void* const* d_in, const int* in_sizes, int n_in,
                              void* d_out, int out_size, void* d_ws, size_t ws_size,
                              hipStream_t stream)
{
    const float* x      = (const float*)d_in[0];
    const float* ch_mem = (const float*)d_in[1];
    const float* ch_wq  = (const float*)d_in[2];
    const float* ch_wk  = (const float*)d_in[3];
    const float* ch_wv  = (const float*)d_in[4];
    const float* sp_mem = (const float*)d_in[5];
    const float* sp_wq  = (const float*)d_in[6];
    const float* sp_wk  = (const float*)d_in[7];
    const float* sp_wv  = (const float*)d_in[8];
    float* out = (float*)d_out;

    ushort* Qb   = (ushort*)d_ws;                 // [12544][256]
    ushort* QFb  = Qb   + (size_t)NBQ * DM;
    ushort* Kb   = QFb  + (size_t)NBQ * DM;       // [2048][256]
    ushort* KFb  = Kb   + (size_t)MM * DM;
    ushort* Vtb  = KFb  + (size_t)MM * DM;        // [256][2048] transposed
    ushort* VFtb = Vtb  + (size_t)MM * DM;
    float*  qm   = (float*)(VFtb + (size_t)MM * DM);
    float*  qv   = qm + NBQ;
    float*  km   = qv + NBQ;
    float*  kv   = km + MM;
    float*  sp_num = kv + MM;                     // [12544][256] f32
    float*  den_ch = sp_num + (size_t)NBQ * DM;   // [12544]
    float*  den_sp = den_ch + NBQ;                // [12544]
    // ws total ~30.1 MB

    // zero the accumulators (out is ch numerator accumulator)
    hipMemsetAsync(out, 0, (size_t)NBQ * DM * sizeof(float), stream);
    hipMemsetAsync(sp_num, 0, ((size_t)NBQ * DM + 2 * NBQ) * sizeof(float), stream);

    dim3 blk(256);
    gemm_proj_all<<<dim3(2080), blk, 0, stream>>>(
        x, ch_mem, ch_wq, ch_wk, ch_wv, sp_mem, sp_wq, sp_wk, sp_wv,
        Qb, QFb, Kb, KFb, Vtb, VFtb);
    row_stats_all<<<dim3((NBQ + MM) / 4), blk, 0, stream>>>(QFb, KFb, qm, qv, km, kv);
    fused_attn_split<<<dim3(784), blk, 0, stream>>>(
        Qb, QFb, Kb, KFb, Vtb, VFtb, qm, qv, km, kv,
        out, sp_num, den_ch, den_sp);
    norm_combine<<<dim3(NBQ * DM / 4 / 256), blk, 0, stream>>>(
        out, sp_num, den_ch, den_sp);
}

// Round 8
// 302.663 us; speedup vs baseline: 1.9780x; 1.9780x over previous
//
#include <hip/hip_runtime.h>

#define NBQ 12544
#define DM  256
#define MM  2048

typedef __attribute__((ext_vector_type(8)))  __bf16 bf16x8;
typedef __attribute__((ext_vector_type(4)))  float  floatx4;

__device__ __forceinline__ ushort f2bf(float x) {
    unsigned u = __float_as_uint(x);
    u += 0x7fffu + ((u >> 16) & 1u);   // RNE
    return (ushort)(u >> 16);
}
__device__ __forceinline__ float bf2f(ushort h) {
    return __uint_as_float(((unsigned)h) << 16);
}

// ---------------- ALL projections in one launch: C = A(fp32) * W(fp32)^T, bf16 out ----
__global__ __launch_bounds__(256) void gemm_proj_all(
    const float* __restrict__ x,      const float* __restrict__ ch_mem,
    const float* __restrict__ ch_wq,  const float* __restrict__ ch_wk,
    const float* __restrict__ ch_wv,  const float* __restrict__ sp_mem,
    const float* __restrict__ sp_wq,  const float* __restrict__ sp_wk,
    const float* __restrict__ sp_wv,
    ushort* __restrict__ Qb,  ushort* __restrict__ QFb,
    ushort* __restrict__ Kb,  ushort* __restrict__ KFb,
    ushort* __restrict__ Vtb, ushort* __restrict__ VFtb)
{
    __shared__ ushort As[64][72];
    __shared__ ushort Ws[64][72];

    int bid = blockIdx.x;
    const float* A; const float* W; ushort* C; int nrows, trans;
    if (bid < 1568) {
        if (bid < 784) { A = x; W = ch_wq; C = Qb; }
        else           { A = x; W = sp_wq; C = QFb; bid -= 784; }
        nrows = NBQ; trans = 0;
    } else if (bid < 1824) {
        if (bid < 1696) { A = ch_mem; W = ch_wk; C = Kb;  bid -= 1568; }
        else            { A = sp_mem; W = sp_wk; C = KFb; bid -= 1696; }
        nrows = MM; trans = 0;
    } else {
        if (bid < 1952) { A = ch_mem; W = ch_wv; C = Vtb;  bid -= 1824; }
        else            { A = sp_mem; W = sp_wv; C = VFtb; bid -= 1952; }
        nrows = MM; trans = 1;
    }
    const int r0 = (bid >> 2) * 64;
    const int c0 = (bid & 3) * 64;

    const int tid  = threadIdx.x;
    const int wv   = tid >> 6;
    const int lane = tid & 63;
    const int quad = lane >> 4;
    const int l16  = lane & 15;
    const int rw = (wv & 1) * 32;
    const int cw = (wv >> 1) * 32;

    floatx4 acc[2][2];
    #pragma unroll
    for (int i = 0; i < 2; ++i)
        #pragma unroll
        for (int j = 0; j < 2; ++j)
            acc[i][j] = (floatx4){0.f, 0.f, 0.f, 0.f};

    for (int d0 = 0; d0 < 256; d0 += 64) {
        __syncthreads();
        #pragma unroll
        for (int it = 0; it < 4; ++it) {
            int idx = tid + it * 256;
            int r = idx >> 4, c4 = (idx & 15) * 4;
            float4 a4 = *(const float4*)(A + (size_t)(r0 + r) * 256 + d0 + c4);
            float4 w4 = *(const float4*)(W + (size_t)(c0 + r) * 256 + d0 + c4);
            ushort4 ab, wb;
            ab.x = f2bf(a4.x); ab.y = f2bf(a4.y); ab.z = f2bf(a4.z); ab.w = f2bf(a4.w);
            wb.x = f2bf(w4.x); wb.y = f2bf(w4.y); wb.z = f2bf(w4.z); wb.w = f2bf(w4.w);
            *(ushort4*)&As[r][c4] = ab;
            *(ushort4*)&Ws[r][c4] = wb;
        }
        __syncthreads();
        #pragma unroll
        for (int kk = 0; kk < 64; kk += 32) {
            bf16x8 aA0 = *(const bf16x8*)&As[rw + l16][kk + quad * 8];
            bf16x8 aA1 = *(const bf16x8*)&As[rw + 16 + l16][kk + quad * 8];
            bf16x8 bW0 = *(const bf16x8*)&Ws[cw + l16][kk + quad * 8];
            bf16x8 bW1 = *(const bf16x8*)&Ws[cw + 16 + l16][kk + quad * 8];
            acc[0][0] = __builtin_amdgcn_mfma_f32_16x16x32_bf16(aA0, bW0, acc[0][0], 0, 0, 0);
            acc[0][1] = __builtin_amdgcn_mfma_f32_16x16x32_bf16(aA0, bW1, acc[0][1], 0, 0, 0);
            acc[1][0] = __builtin_amdgcn_mfma_f32_16x16x32_bf16(aA1, bW0, acc[1][0], 0, 0, 0);
            acc[1][1] = __builtin_amdgcn_mfma_f32_16x16x32_bf16(aA1, bW1, acc[1][1], 0, 0, 0);
        }
    }

    if (!trans) {
        #pragma unroll
        for (int ag = 0; ag < 2; ++ag)
            #pragma unroll
            for (int cg = 0; cg < 2; ++cg)
                #pragma unroll
                for (int i = 0; i < 4; ++i)
                    C[(size_t)(r0 + rw + ag * 16 + quad * 4 + i) * 256
                      + c0 + cw + cg * 16 + l16] = f2bf(acc[ag][cg][i]);
    } else {
        __syncthreads();
        #pragma unroll
        for (int ag = 0; ag < 2; ++ag)
            #pragma unroll
            for (int cg = 0; cg < 2; ++cg)
                #pragma unroll
                for (int i = 0; i < 4; ++i)
                    Ws[cw + cg * 16 + l16][rw + ag * 16 + quad * 4 + i] = f2bf(acc[ag][cg][i]);
        __syncthreads();
        const int col = tid >> 2;
        const int seg = (tid & 3) * 16;
        #pragma unroll
        for (int j = 0; j < 2; ++j)
            *(uint4*)(C + (size_t)(c0 + col) * nrows + r0 + seg + j * 8) =
                *(const uint4*)&Ws[col][seg + j * 8];
    }
}

// ---------------- row stats (QF rows then KF rows), one launch ----------------
__global__ __launch_bounds__(256) void row_stats_all(
    const ushort* __restrict__ QFb, const ushort* __restrict__ KFb,
    float* __restrict__ qm, float* __restrict__ qv,
    float* __restrict__ km, float* __restrict__ kv)
{
    const int rt   = blockIdx.x * 4 + (threadIdx.x >> 6);
    const int lane = threadIdx.x & 63;
    const ushort* X; float* mean; float* var; int row;
    if (rt < NBQ) { X = QFb; mean = qm; var = qv; row = rt; }
    else          { X = KFb; mean = km; var = kv; row = rt - NBQ; }
    ushort4 u = *(const ushort4*)(X + (size_t)row * 256 + lane * 4);
    float a = bf2f(u.x), b = bf2f(u.y), c = bf2f(u.z), d = bf2f(u.w);
    float s  = a + b + c + d;
    float ss = a * a + b * b + c * c + d * d;
    #pragma unroll
    for (int off = 32; off > 0; off >>= 1) {
        s  += __shfl_down(s, off);
        ss += __shfl_down(ss, off);
    }
    if (lane == 0) {
        float m = s * (1.f / 256.f);
        mean[row] = m;
        var[row]  = (ss - 256.f * m * m) * (1.f / 255.f);
    }
}

// ---------------- fused attention: single branch, 32q blocks, 32-key tiles ----------
// grid 784 = 392 q-blocks x 2 branches; LDS 40,192 B -> 3 blocks/CU (768 slots) ->
// ~1 balanced dispatch round, 12 waves/CU. All blocks walk keys 0..2047 in lockstep
// (L2 reuse, r6-proven). Each block completes its branch's softmax locally; branches
// combine via atomicAdd into memset-zeroed out (2 adds/elem, deterministic).
// Score waves: (qh=wv&1, kh=wv>>1) -> 16q x 16k, K=256, 16x16x32 MFMA (r2-verified
// layouts). PV waves: d-quarter = wv*64, both q-halves, K=32 in one MFMA.
__global__ __launch_bounds__(256, 3) void fused_attn_32q(
    const ushort* __restrict__ Qb,  const ushort* __restrict__ QFb,
    const ushort* __restrict__ Kb,  const ushort* __restrict__ KFb,
    const ushort* __restrict__ Vtb, const ushort* __restrict__ VFtb,
    const float* __restrict__ qm_, const float* __restrict__ qv_,
    const float* __restrict__ km_, const float* __restrict__ kv_,
    float* __restrict__ out)
{
    __shared__ ushort K_lds[32][264];   // 528B stride -> uniform banks (r2-proven)
    __shared__ ushort Vt_lds[256][40];  // [d][key], 80B stride -> uniform (checked)
    __shared__ ushort P_lds[32][40];    // [q][key]
    __shared__ float  denbuf[2][32];    // [kh][q]
    // total LDS = 16896 + 20480 + 2560 + 256 = 40192 B -> 3 blocks/CU

    const int tid  = threadIdx.x;
    const int wv   = tid >> 6;
    const int lane = tid & 63;
    const int quad = lane >> 4;
    const int l16  = lane & 15;
    const int qh   = wv & 1;    // score q-half
    const int kh   = wv >> 1;   // score k-half

    const bool spatial = (blockIdx.x >= 392);
    const int q0 = (spatial ? (int)blockIdx.x - 392 : (int)blockIdx.x) * 32;
    const ushort* Qp = spatial ? QFb  : Qb;
    const ushort* Kp = spatial ? KFb  : Kb;
    const ushort* Vp = spatial ? VFtb : Vtb;

    // Q A-fragments in registers (one branch): A[m=l16][k=quad*8+j], K=256 -> 8 frags
    bf16x8 aQ[8];
    {
        const ushort* qp = Qp + (size_t)(q0 + qh * 16 + l16) * DM + quad * 8;
        #pragma unroll
        for (int s = 0; s < 8; ++s) aQ[s] = *(const bf16x8*)(qp + s * 32);
    }
    float qmr[4], qvr[4];
    if (spatial) {
        #pragma unroll
        for (int r = 0; r < 4; ++r) {
            int row = q0 + qh * 16 + quad * 4 + r;
            qmr[r] = qm_[row]; qvr[r] = qv_[row];
        }
    }

    floatx4 accO[2][4];    // [q-half][d-subtile], d-quarter = wv*64
    #pragma unroll
    for (int a = 0; a < 2; ++a)
        #pragma unroll
        for (int b = 0; b < 4; ++b)
            accO[a][b] = (floatx4){0.f, 0.f, 0.f, 0.f};
    float den_r[4] = {0.f, 0.f, 0.f, 0.f};

    for (int kt = 0; kt < MM; kt += 32) {
        __syncthreads();  // prev tile's K/Vt/P reads done
        // stage K (32 x 256): 1024 uint4 = 32 rows x 32 chunks
        #pragma unroll
        for (int it = 0; it < 4; ++it) {
            int idx = tid + it * 256;
            int r = idx >> 5, c8 = (idx & 31) * 8;
            *(uint4*)&K_lds[r][c8] = *(const uint4*)(Kp + (size_t)(kt + r) * DM + c8);
        }
        // stage Vt (256 d x 32 keys): 1024 uint4 = 256 rows x 4 chunks
        #pragma unroll
        for (int it = 0; it < 4; ++it) {
            int idx = tid + it * 256;
            int d = idx >> 2, kc = idx & 3;
            *(uint4*)&Vt_lds[d][kc * 8] = *(const uint4*)(Vp + (size_t)d * MM + kt + kc * 8);
        }
        __syncthreads();

        // ---- scores: 16q x 16k per wave, K=256 ----
        floatx4 S = (floatx4){0.f, 0.f, 0.f, 0.f};
        #pragma unroll
        for (int s = 0; s < 8; ++s) {
            bf16x8 bK = *(const bf16x8*)&K_lds[kh * 16 + l16][s * 32 + quad * 8];
            S = __builtin_amdgcn_mfma_f32_16x16x32_bf16(aQ[s], bK, S, 0, 0, 0);
        }
        // ---- epilogue -> P (bf16) + den partials. C-layout: col=l16(k), row=quad*4+r(q)
        {
            int kcol = kt + kh * 16 + l16;
            float kmv = 0.f, kvv = 0.f;
            if (spatial) { kmv = km_[kcol]; kvv = kv_[kcol]; }
            #pragma unroll
            for (int r = 0; r < 4; ++r) {
                float p;
                if (!spatial) {
                    p = __expf(S[r] * 0.0625f);
                } else {
                    float mp  = qmr[r] * kmv;
                    float cov = (S[r] - 256.f * mp) * (1.f / 255.f);
                    float num = (2.f * mp + 0.01f) * (2.f * cov + 0.03f);
                    float den = (qmr[r] * qmr[r] + kmv * kmv + 0.01f) * (qvr[r] + kvv + 0.03f);
                    p = __expf(num / (den + 1e-8f));
                }
                P_lds[qh * 16 + quad * 4 + r][kh * 16 + l16] = f2bf(p);
                den_r[r] += p;
            }
        }
        __syncthreads();

        // ---- PV: wave = d-quarter (wv*64), A = P (both q-halves), K=32, one MFMA each
        bf16x8 aP0 = *(const bf16x8*)&P_lds[l16][quad * 8];
        bf16x8 aP1 = *(const bf16x8*)&P_lds[16 + l16][quad * 8];
        #pragma unroll
        for (int ds = 0; ds < 4; ++ds) {
            bf16x8 bV = *(const bf16x8*)&Vt_lds[wv * 64 + ds * 16 + l16][quad * 8];
            accO[0][ds] = __builtin_amdgcn_mfma_f32_16x16x32_bf16(aP0, bV, accO[0][ds], 0, 0, 0);
            accO[1][ds] = __builtin_amdgcn_mfma_f32_16x16x32_bf16(aP1, bV, accO[1][ds], 0, 0, 0);
        }
    }

    // ---- denominators: reduce over the wave's 16 k-cols, combine k-halves via LDS --
    #pragma unroll
    for (int r = 0; r < 4; ++r)
        #pragma unroll
        for (int m = 1; m < 16; m <<= 1)
            den_r[r] += __shfl_xor(den_r[r], m, 64);
    if (l16 == 0) {
        #pragma unroll
        for (int r = 0; r < 4; ++r)
            denbuf[kh][qh * 16 + quad * 4 + r] = den_r[r];
    }
    __syncthreads();

    // ---- output: normalize + atomicAdd combine (2 adds/element, deterministic) ----
    // PV C-layout: col=l16 (d within subtile), row=quad*4+r (q within half)
    #pragma unroll
    for (int qt = 0; qt < 2; ++qt) {
        #pragma unroll
        for (int r = 0; r < 4; ++r) {
            int rloc = qt * 16 + quad * 4 + r;
            float rden = 1.f / (denbuf[0][rloc] + denbuf[1][rloc]);
            #pragma unroll
            for (int ds = 0; ds < 4; ++ds)
                atomicAdd(out + (size_t)(q0 + rloc) * DM + wv * 64 + ds * 16 + l16,
                          accO[qt][ds][r] * rden);
        }
    }
}

extern "C" void kernel_launch(void* const* d_in, const int* in_sizes, int n_in,
                              void* d_out, int out_size, void* d_ws, size_t ws_size,
                              hipStream_t stream)
{
    const float* x      = (const float*)d_in[0];
    const float* ch_mem = (const float*)d_in[1];
    const float* ch_wq  = (const float*)d_in[2];
    const float* ch_wk  = (const float*)d_in[3];
    const float* ch_wv  = (const float*)d_in[4];
    const float* sp_mem = (const float*)d_in[5];
    const float* sp_wq  = (const float*)d_in[6];
    const float* sp_wk  = (const float*)d_in[7];
    const float* sp_wv  = (const float*)d_in[8];
    float* out = (float*)d_out;

    ushort* Qb   = (ushort*)d_ws;                 // [12544][256]
    ushort* QFb  = Qb   + (size_t)NBQ * DM;
    ushort* Kb   = QFb  + (size_t)NBQ * DM;       // [2048][256]
    ushort* KFb  = Kb   + (size_t)MM * DM;
    ushort* Vtb  = KFb  + (size_t)MM * DM;        // [256][2048] transposed
    ushort* VFtb = Vtb  + (size_t)MM * DM;
    float*  qm   = (float*)(VFtb + (size_t)MM * DM);
    float*  qv   = qm + NBQ;
    float*  km   = qv + NBQ;
    float*  kv   = km + MM;

    hipMemsetAsync(out, 0, (size_t)NBQ * DM * sizeof(float), stream);

    dim3 blk(256);
    gemm_proj_all<<<dim3(2080), blk, 0, stream>>>(
        x, ch_mem, ch_wq, ch_wk, ch_wv, sp_mem, sp_wq, sp_wk, sp_wv,
        Qb, QFb, Kb, KFb, Vtb, VFtb);
    row_stats_all<<<dim3((NBQ + MM) / 4), blk, 0, stream>>>(QFb, KFb, qm, qv, km, kv);
    fused_attn_32q<<<dim3(784), blk, 0, stream>>>(
        Qb, QFb, Kb, KFb, Vtb, VFtb, qm, qv, km, kv, out);
}

// Round 9
// 280.238 us; speedup vs baseline: 2.1362x; 1.0800x over previous
//
#include <hip/hip_runtime.h>

#define NBQ 12544
#define DM  256
#define MM  2048

typedef __attribute__((ext_vector_type(8)))  __bf16 bf16x8;
typedef __attribute__((ext_vector_type(4)))  float  floatx4;

__device__ __forceinline__ ushort f2bf(float x) {
    unsigned u = __float_as_uint(x);
    u += 0x7fffu + ((u >> 16) & 1u);   // RNE
    return (ushort)(u >> 16);
}
__device__ __forceinline__ float bf2f(ushort h) {
    return __uint_as_float(((unsigned)h) << 16);
}

// ---------------- ALL projections in one launch: C = A(fp32) * W(fp32)^T, bf16 out ----
__global__ __launch_bounds__(256) void gemm_proj_all(
    const float* __restrict__ x,      const float* __restrict__ ch_mem,
    const float* __restrict__ ch_wq,  const float* __restrict__ ch_wk,
    const float* __restrict__ ch_wv,  const float* __restrict__ sp_mem,
    const float* __restrict__ sp_wq,  const float* __restrict__ sp_wk,
    const float* __restrict__ sp_wv,
    ushort* __restrict__ Qb,  ushort* __restrict__ QFb,
    ushort* __restrict__ Kb,  ushort* __restrict__ KFb,
    ushort* __restrict__ Vtb, ushort* __restrict__ VFtb)
{
    __shared__ ushort As[64][72];
    __shared__ ushort Ws[64][72];

    int bid = blockIdx.x;
    const float* A; const float* W; ushort* C; int nrows, trans;
    if (bid < 1568) {
        if (bid < 784) { A = x; W = ch_wq; C = Qb; }
        else           { A = x; W = sp_wq; C = QFb; bid -= 784; }
        nrows = NBQ; trans = 0;
    } else if (bid < 1824) {
        if (bid < 1696) { A = ch_mem; W = ch_wk; C = Kb;  bid -= 1568; }
        else            { A = sp_mem; W = sp_wk; C = KFb; bid -= 1696; }
        nrows = MM; trans = 0;
    } else {
        if (bid < 1952) { A = ch_mem; W = ch_wv; C = Vtb;  bid -= 1824; }
        else            { A = sp_mem; W = sp_wv; C = VFtb; bid -= 1952; }
        nrows = MM; trans = 1;
    }
    const int r0 = (bid >> 2) * 64;
    const int c0 = (bid & 3) * 64;

    const int tid  = threadIdx.x;
    const int wv   = tid >> 6;
    const int lane = tid & 63;
    const int quad = lane >> 4;
    const int l16  = lane & 15;
    const int rw = (wv & 1) * 32;
    const int cw = (wv >> 1) * 32;

    floatx4 acc[2][2];
    #pragma unroll
    for (int i = 0; i < 2; ++i)
        #pragma unroll
        for (int j = 0; j < 2; ++j)
            acc[i][j] = (floatx4){0.f, 0.f, 0.f, 0.f};

    for (int d0 = 0; d0 < 256; d0 += 64) {
        __syncthreads();
        #pragma unroll
        for (int it = 0; it < 4; ++it) {
            int idx = tid + it * 256;
            int r = idx >> 4, c4 = (idx & 15) * 4;
            float4 a4 = *(const float4*)(A + (size_t)(r0 + r) * 256 + d0 + c4);
            float4 w4 = *(const float4*)(W + (size_t)(c0 + r) * 256 + d0 + c4);
            ushort4 ab, wb;
            ab.x = f2bf(a4.x); ab.y = f2bf(a4.y); ab.z = f2bf(a4.z); ab.w = f2bf(a4.w);
            wb.x = f2bf(w4.x); wb.y = f2bf(w4.y); wb.z = f2bf(w4.z); wb.w = f2bf(w4.w);
            *(ushort4*)&As[r][c4] = ab;
            *(ushort4*)&Ws[r][c4] = wb;
        }
        __syncthreads();
        #pragma unroll
        for (int kk = 0; kk < 64; kk += 32) {
            bf16x8 aA0 = *(const bf16x8*)&As[rw + l16][kk + quad * 8];
            bf16x8 aA1 = *(const bf16x8*)&As[rw + 16 + l16][kk + quad * 8];
            bf16x8 bW0 = *(const bf16x8*)&Ws[cw + l16][kk + quad * 8];
            bf16x8 bW1 = *(const bf16x8*)&Ws[cw + 16 + l16][kk + quad * 8];
            acc[0][0] = __builtin_amdgcn_mfma_f32_16x16x32_bf16(aA0, bW0, acc[0][0], 0, 0, 0);
            acc[0][1] = __builtin_amdgcn_mfma_f32_16x16x32_bf16(aA0, bW1, acc[0][1], 0, 0, 0);
            acc[1][0] = __builtin_amdgcn_mfma_f32_16x16x32_bf16(aA1, bW0, acc[1][0], 0, 0, 0);
            acc[1][1] = __builtin_amdgcn_mfma_f32_16x16x32_bf16(aA1, bW1, acc[1][1], 0, 0, 0);
        }
    }

    if (!trans) {
        #pragma unroll
        for (int ag = 0; ag < 2; ++ag)
            #pragma unroll
            for (int cg = 0; cg < 2; ++cg)
                #pragma unroll
                for (int i = 0; i < 4; ++i)
                    C[(size_t)(r0 + rw + ag * 16 + quad * 4 + i) * 256
                      + c0 + cw + cg * 16 + l16] = f2bf(acc[ag][cg][i]);
    } else {
        __syncthreads();
        #pragma unroll
        for (int ag = 0; ag < 2; ++ag)
            #pragma unroll
            for (int cg = 0; cg < 2; ++cg)
                #pragma unroll
                for (int i = 0; i < 4; ++i)
                    Ws[cw + cg * 16 + l16][rw + ag * 16 + quad * 4 + i] = f2bf(acc[ag][cg][i]);
        __syncthreads();
        const int col = tid >> 2;
        const int seg = (tid & 3) * 16;
        #pragma unroll
        for (int j = 0; j < 2; ++j)
            *(uint4*)(C + (size_t)(c0 + col) * nrows + r0 + seg + j * 8) =
                *(const uint4*)&Ws[col][seg + j * 8];
    }
}

// ---------------- row stats (QF rows then KF rows), one launch ----------------
__global__ __launch_bounds__(256) void row_stats_all(
    const ushort* __restrict__ QFb, const ushort* __restrict__ KFb,
    float* __restrict__ qm, float* __restrict__ qv,
    float* __restrict__ km, float* __restrict__ kv)
{
    const int rt   = blockIdx.x * 4 + (threadIdx.x >> 6);
    const int lane = threadIdx.x & 63;
    const ushort* X; float* mean; float* var; int row;
    if (rt < NBQ) { X = QFb; mean = qm; var = qv; row = rt; }
    else          { X = KFb; mean = km; var = kv; row = rt - NBQ; }
    ushort4 u = *(const ushort4*)(X + (size_t)row * 256 + lane * 4);
    float a = bf2f(u.x), b = bf2f(u.y), c = bf2f(u.z), d = bf2f(u.w);
    float s  = a + b + c + d;
    float ss = a * a + b * b + c * c + d * d;
    #pragma unroll
    for (int off = 32; off > 0; off >>= 1) {
        s  += __shfl_down(s, off);
        ss += __shfl_down(ss, off);
    }
    if (lane == 0) {
        float m = s * (1.f / 256.f);
        mean[row] = m;
        var[row]  = (ss - 256.f * m * m) * (1.f / 255.f);
    }
}

// ---------------- fused dual attention (r2 structure), P stride 36 ----------------
// Block: 32 queries, 4 waves, BOTH branches (K/V staging amortized over 2 branches).
// Wave w: qsel=w&1 (score q-half / PV q-half), ksel=w>>1 (score k-half / PV d-half).
// P_lds rows are 36 ushorts (72 B): quad step = 288 B = 72 dwords = 8 mod 32 ->
// scalar P-stores from the 4 quads hit disjoint bank octets (was 4-way at stride 40).
__global__ __launch_bounds__(256, 2) void fused_attn_mfma(
    const ushort* __restrict__ Qb,  const ushort* __restrict__ QFb,
    const ushort* __restrict__ Kb,  const ushort* __restrict__ KFb,
    const ushort* __restrict__ Vtb, const ushort* __restrict__ VFtb,
    const float* __restrict__ qm_, const float* __restrict__ qv_,
    const float* __restrict__ km_, const float* __restrict__ kv_,
    float* __restrict__ out)
{
    __shared__ ushort K_lds[32][264];     // 528B stride -> uniform banks (r2-proven)
    __shared__ ushort KF_lds[32][264];
    __shared__ ushort Vt_lds[256][40];    // [d][key], 80B stride
    __shared__ ushort VFt_lds[256][40];
    __shared__ ushort P_lds[2][32][36];   // [branch][q][key], 72B stride (quad-disjoint)
    // total LDS = 33792 + 40960 + 4608 = 79360 B -> 2 blocks/CU

    const int tid  = threadIdx.x;
    const int wv   = tid >> 6;
    const int lane = tid & 63;
    const int quad = lane >> 4;
    const int l16  = lane & 15;
    const int qsel = wv & 1;
    const int ksel = wv >> 1;
    const int q0   = blockIdx.x * 32;

    // Q A-fragments in registers for the whole key loop
    bf16x8 aQ[8], aQF[8];
    {
        const ushort* qp  = Qb  + (size_t)(q0 + qsel * 16 + l16) * DM + quad * 8;
        const ushort* qfp = QFb + (size_t)(q0 + qsel * 16 + l16) * DM + quad * 8;
        #pragma unroll
        for (int s = 0; s < 8; ++s) {
            aQ[s]  = *(const bf16x8*)(qp  + s * 32);
            aQF[s] = *(const bf16x8*)(qfp + s * 32);
        }
    }
    float qmv[4], qvv[4];
    #pragma unroll
    for (int r = 0; r < 4; ++r) {
        int qg = q0 + qsel * 16 + quad * 4 + r;
        qmv[r] = qm_[qg]; qvv[r] = qv_[qg];
    }

    floatx4 acc_c[8], acc_s[8];
    #pragma unroll
    for (int t = 0; t < 8; ++t) {
        acc_c[t] = (floatx4){0.f, 0.f, 0.f, 0.f};
        acc_s[t] = (floatx4){0.f, 0.f, 0.f, 0.f};
    }
    float denc_r[4] = {0.f, 0.f, 0.f, 0.f};
    float dens_r[4] = {0.f, 0.f, 0.f, 0.f};

    for (int kt = 0; kt < MM; kt += 32) {
        __syncthreads();  // previous tile's LDS fully consumed
        // stage K/KF (32 x 256): 1024 uint4-chunks = 32 rows x 32 chunks
        #pragma unroll
        for (int it = 0; it < 4; ++it) {
            int idx = tid + it * 256;
            int r = idx >> 5, c8 = (idx & 31) * 8;
            *(uint4*)&K_lds[r][c8]  = *(const uint4*)(Kb  + (size_t)(kt + r) * DM + c8);
            *(uint4*)&KF_lds[r][c8] = *(const uint4*)(KFb + (size_t)(kt + r) * DM + c8);
        }
        // stage Vt/VFt (256 dims x 32 keys): 1024 uint4 = 256 rows x 4 chunks
        #pragma unroll
        for (int it = 0; it < 4; ++it) {
            int idx = tid + it * 256;
            int d = idx >> 2, kc = (idx & 3) * 8;
            *(uint4*)&Vt_lds[d][kc]  = *(const uint4*)(Vtb  + (size_t)d * MM + kt + kc);
            *(uint4*)&VFt_lds[d][kc] = *(const uint4*)(VFtb + (size_t)d * MM + kt + kc);
        }
        __syncthreads();

        // ---- scores: 16q x 16k per wave, both branches ----
        floatx4 sc = (floatx4){0.f, 0.f, 0.f, 0.f};
        floatx4 sd = (floatx4){0.f, 0.f, 0.f, 0.f};
        #pragma unroll
        for (int s = 0; s < 8; ++s) {
            bf16x8 bK  = *(const bf16x8*)&K_lds[ksel * 16 + l16][s * 32 + quad * 8];
            bf16x8 bKF = *(const bf16x8*)&KF_lds[ksel * 16 + l16][s * 32 + quad * 8];
            sc = __builtin_amdgcn_mfma_f32_16x16x32_bf16(aQ[s],  bK,  sc, 0, 0, 0);
            sd = __builtin_amdgcn_mfma_f32_16x16x32_bf16(aQF[s], bKF, sd, 0, 0, 0);
        }
        // ---- epilogue: exp(score/16), SSIM -> P (bf16), denominator partials ----
        {
            float kmv = km_[kt + ksel * 16 + l16];
            float kvv = kv_[kt + ksel * 16 + l16];
            #pragma unroll
            for (int r = 0; r < 4; ++r) {
                float p1  = __expf(sc[r] * 0.0625f);
                float mp  = qmv[r] * kmv;
                float cov = (sd[r] - 256.f * mp) * (1.f / 255.f);
                float num = (2.f * mp + 0.01f) * (2.f * cov + 0.03f);
                float den = (qmv[r] * qmv[r] + kmv * kmv + 0.01f) * (qvv[r] + kvv + 0.03f);
                float p2  = __expf(num / (den + 1e-8f));
                P_lds[0][qsel * 16 + quad * 4 + r][ksel * 16 + l16] = f2bf(p1);
                P_lds[1][qsel * 16 + quad * 4 + r][ksel * 16 + l16] = f2bf(p2);
                denc_r[r] += p1;
                dens_r[r] += p2;
            }
        }
        __syncthreads();
        // ---- PV: A = P rows (own q-half), B = Vt (own d-half), K=32 in one step ----
        bf16x8 aPc = *(const bf16x8*)&P_lds[0][qsel * 16 + l16][quad * 8];
        bf16x8 aPs = *(const bf16x8*)&P_lds[1][qsel * 16 + l16][quad * 8];
        #pragma unroll
        for (int t = 0; t < 8; ++t) {
            int d0 = ksel * 128 + t * 16;
            bf16x8 bV  = *(const bf16x8*)&Vt_lds[d0 + l16][quad * 8];
            bf16x8 bVF = *(const bf16x8*)&VFt_lds[d0 + l16][quad * 8];
            acc_c[t] = __builtin_amdgcn_mfma_f32_16x16x32_bf16(aPc, bV,  acc_c[t], 0, 0, 0);
            acc_s[t] = __builtin_amdgcn_mfma_f32_16x16x32_bf16(aPs, bVF, acc_s[t], 0, 0, 0);
        }
    }

    // ---- denominators: reduce over 16 key-lanes, combine k-halves via LDS ----
    #pragma unroll
    for (int r = 0; r < 4; ++r) {
        #pragma unroll
        for (int m = 1; m < 16; m <<= 1) {
            denc_r[r] += __shfl_xor(denc_r[r], m, 64);
            dens_r[r] += __shfl_xor(dens_r[r], m, 64);
        }
    }
    __syncthreads();  // all PV reads of P done; safe to alias
    float* denbuf = (float*)P_lds;  // [2 branch][2 ksel][32 q]
    if (l16 == 0) {
        #pragma unroll
        for (int r = 0; r < 4; ++r) {
            int q32 = qsel * 16 + quad * 4 + r;
            denbuf[ksel * 32 + q32]      = denc_r[r];
            denbuf[64 + ksel * 32 + q32] = dens_r[r];
        }
    }
    __syncthreads();
    #pragma unroll
    for (int r = 0; r < 4; ++r) {
        int q32 = qsel * 16 + quad * 4 + r;
        float rc = 1.f / (denbuf[q32] + denbuf[32 + q32]);
        float rs = 1.f / (denbuf[64 + q32] + denbuf[96 + q32]);
        float* orow = out + (size_t)(q0 + q32) * DM + ksel * 128 + l16;
        #pragma unroll
        for (int t = 0; t < 8; ++t)
            orow[t * 16] = acc_c[t][r] * rc + acc_s[t][r] * rs;
    }
}

extern "C" void kernel_launch(void* const* d_in, const int* in_sizes, int n_in,
                              void* d_out, int out_size, void* d_ws, size_t ws_size,
                              hipStream_t stream)
{
    const float* x      = (const float*)d_in[0];
    const float* ch_mem = (const float*)d_in[1];
    const float* ch_wq  = (const float*)d_in[2];
    const float* ch_wk  = (const float*)d_in[3];
    const float* ch_wv  = (const float*)d_in[4];
    const float* sp_mem = (const float*)d_in[5];
    const float* sp_wq  = (const float*)d_in[6];
    const float* sp_wk  = (const float*)d_in[7];
    const float* sp_wv  = (const float*)d_in[8];
    float* out = (float*)d_out;

    ushort* Qb   = (ushort*)d_ws;                 // [12544][256]
    ushort* QFb  = Qb   + (size_t)NBQ * DM;
    ushort* Kb   = QFb  + (size_t)NBQ * DM;       // [2048][256]
    ushort* KFb  = Kb   + (size_t)MM * DM;
    ushort* Vtb  = KFb  + (size_t)MM * DM;        // [256][2048] transposed
    ushort* VFtb = Vtb  + (size_t)MM * DM;
    float*  qm   = (float*)(VFtb + (size_t)MM * DM);
    float*  qv   = qm + NBQ;
    float*  km   = qv + NBQ;
    float*  kv   = km + MM;

    dim3 blk(256);
    gemm_proj_all<<<dim3(2080), blk, 0, stream>>>(
        x, ch_mem, ch_wq, ch_wk, ch_wv, sp_mem, sp_wq, sp_wk, sp_wv,
        Qb, QFb, Kb, KFb, Vtb, VFtb);
    row_stats_all<<<dim3((NBQ + MM) / 4), blk, 0, stream>>>(QFb, KFb, qm, qv, km, kv);
    fused_attn_mfma<<<dim3(NBQ / 32), blk, 0, stream>>>(
        Qb, QFb, Kb, KFb, Vtb, VFtb, qm, qv, km, kv, out);
}